// Round 2
// baseline (151.841 us; speedup 1.0000x reference)
//
#include <hip/hip_runtime.h>

#define NATOMS 8192
#define MAXP (64 * NATOMS) /* 524288 */
#define R2CUT 25.0f

constexpr int BLOCK = 512;               // 8 waves
constexpr int WAVES = BLOCK / 64;        // rows per block
constexpr int JT = 2048;                 // j-tile staged in LDS
constexpr int NBLOCKS = NATOMS / WAVES;  // 1024

// ---------------------------------------------------------------------------
// Pair predicate must match float32 numpy bit-exactly: no FMA contraction.
// d2 = ((dx*dx + dy*dy) + dz*dz), all round-to-nearest f32 ops.
// ---------------------------------------------------------------------------

__global__ __launch_bounds__(256) void nl_init(float4* __restrict__ out) {
    // out layout (floats): [0,2*MAXP) edge_index -> -1, [2*MAXP,6*MAXP) -> 0
    const int total4 = 6 * MAXP / 4;    // 786432
    const int neg4   = 2 * MAXP / 4;    // 262144
    const float4 negv = make_float4(-1.f, -1.f, -1.f, -1.f);
    const float4 zerov = make_float4(0.f, 0.f, 0.f, 0.f);
    int idx = blockIdx.x * blockDim.x + threadIdx.x;
    int stride = gridDim.x * blockDim.x;
    for (int k = idx; k < total4; k += stride)
        out[k] = (k < neg4) ? negv : zerov;
}

__global__ __launch_bounds__(512) void nl_count(const float* __restrict__ pos,
                                                const int* __restrict__ batch,
                                                int* __restrict__ counts) {
    __shared__ float sp[JT * 3];
    __shared__ int   sb[JT];
    const int tid  = threadIdx.x;
    const int lane = tid & 63;
    const int wave = tid >> 6;
    const int i = blockIdx.x * WAVES + wave;
    const float xi = pos[3 * i + 0];
    const float yi = pos[3 * i + 1];
    const float zi = pos[3 * i + 2];
    const int bi = batch[i];
    int cnt = 0;
    for (int t = 0; t < NATOMS / JT; ++t) {
        const int j0 = t * JT;
        const float4* g4 = reinterpret_cast<const float4*>(pos + 3 * j0);
        float4* s4 = reinterpret_cast<float4*>(sp);
        for (int k = tid; k < JT * 3 / 4; k += BLOCK) s4[k] = g4[k];
        for (int k = tid; k < JT; k += BLOCK) sb[k] = batch[j0 + k];
        __syncthreads();
        for (int jj = lane; jj < JT; jj += 64) {
            const int j = j0 + jj;
            const float dx = xi - sp[3 * jj + 0];
            const float dy = yi - sp[3 * jj + 1];
            const float dz = zi - sp[3 * jj + 2];
            const float d2 = __fadd_rn(
                __fadd_rn(__fmul_rn(dx, dx), __fmul_rn(dy, dy)),
                __fmul_rn(dz, dz));
            cnt += (j != i && sb[jj] == bi && d2 < R2CUT) ? 1 : 0;
        }
        __syncthreads();
    }
    for (int off = 32; off; off >>= 1) cnt += __shfl_down(cnt, off);
    if (lane == 0) counts[i] = cnt;
}

__global__ __launch_bounds__(256) void nl_scan(const int* __restrict__ counts,
                                               int* __restrict__ offsets) {
    // exclusive prefix sum over 8192 ints, one block of 256 threads x 32 each
    __shared__ int ssum[256];
    const int tid = threadIdx.x;
    const int base = tid * 32;
    int c[32];
    int s = 0;
#pragma unroll
    for (int k = 0; k < 32; ++k) { c[k] = counts[base + k]; s += c[k]; }
    ssum[tid] = s;
    __syncthreads();
    for (int off = 1; off < 256; off <<= 1) {
        int v = (tid >= off) ? ssum[tid - off] : 0;
        __syncthreads();
        ssum[tid] += v;
        __syncthreads();
    }
    int run = ssum[tid] - s;  // exclusive
#pragma unroll
    for (int k = 0; k < 32; ++k) { offsets[base + k] = run; run += c[k]; }
}

__global__ __launch_bounds__(512) void nl_fill(const float* __restrict__ pos,
                                               const int* __restrict__ batch,
                                               const int* __restrict__ offsets,
                                               float* __restrict__ out) {
    __shared__ float sp[JT * 3];
    __shared__ int   sb[JT];
    const int tid  = threadIdx.x;
    const int lane = tid & 63;
    const int wave = tid >> 6;
    const int i = blockIdx.x * WAVES + wave;
    const float xi = pos[3 * i + 0];
    const float yi = pos[3 * i + 1];
    const float zi = pos[3 * i + 2];
    const int bi = batch[i];
    int fill = offsets[i];
    float* __restrict__ outI = out;
    float* __restrict__ outJ = out + MAXP;
    float* __restrict__ outW = out + 2 * MAXP;
    float* __restrict__ outV = out + 3 * MAXP;
    const float fi = (float)i;
    for (int t = 0; t < NATOMS / JT; ++t) {
        const int j0 = t * JT;
        const float4* g4 = reinterpret_cast<const float4*>(pos + 3 * j0);
        float4* s4 = reinterpret_cast<float4*>(sp);
        for (int k = tid; k < JT * 3 / 4; k += BLOCK) s4[k] = g4[k];
        for (int k = tid; k < JT; k += BLOCK) sb[k] = batch[j0 + k];
        __syncthreads();
        for (int jj = lane; jj < JT; jj += 64) {
            const int j = j0 + jj;
            const float dx = xi - sp[3 * jj + 0];
            const float dy = yi - sp[3 * jj + 1];
            const float dz = zi - sp[3 * jj + 2];
            const float d2 = __fadd_rn(
                __fadd_rn(__fmul_rn(dx, dx), __fmul_rn(dy, dy)),
                __fmul_rn(dz, dz));
            const bool m = (j != i) && (sb[jj] == bi) && (d2 < R2CUT);
            const unsigned long long b = __ballot(m);
            if (m) {
                const int slot =
                    fill + __popcll(b & ((1ull << lane) - 1ull));
                if (slot < MAXP) {
                    outI[slot] = fi;
                    outJ[slot] = (float)j;
                    outW[slot] = sqrtf(d2);
                    outV[3 * slot + 0] = dx;
                    outV[3 * slot + 1] = dy;
                    outV[3 * slot + 2] = dz;
                }
            }
            fill += __popcll(b);
        }
        __syncthreads();
    }
}

extern "C" void kernel_launch(void* const* d_in, const int* in_sizes, int n_in,
                              void* d_out, int out_size, void* d_ws, size_t ws_size,
                              hipStream_t stream) {
    const float* pos = (const float*)d_in[0];
    const int* batch = (const int*)d_in[1];
    float* out = (float*)d_out;
    int* counts = (int*)d_ws;
    int* offsets = counts + NATOMS;

    nl_init<<<2048, 256, 0, stream>>>((float4*)out);
    nl_count<<<NBLOCKS, BLOCK, 0, stream>>>(pos, batch, counts);
    nl_scan<<<1, 256, 0, stream>>>(counts, offsets);
    nl_fill<<<NBLOCKS, BLOCK, 0, stream>>>(pos, batch, offsets, out);
}

// Round 3
// 98.961 us; speedup vs baseline: 1.5344x; 1.5344x over previous
//
#include <hip/hip_runtime.h>

#define NATOMS 8192
#define MAXP (64 * NATOMS) /* 524288 */
#define R2CUT 25.0f

constexpr int ROWW = 128;   // per-row j-list capacity (expected ~47, 11-sigma safe)
constexpr int NC1 = 9;      // cells per axis (45.0 / 5.0)
constexpr int NCELL = NC1 * NC1 * NC1;  // 729

// Pair predicate must match float32 numpy bit-exactly: no FMA contraction.
// d2 = ((dx*dx + dy*dy) + dz*dz), all round-to-nearest f32 ops.
__device__ __forceinline__ float d2_exact(float dx, float dy, float dz) {
    return __fadd_rn(__fadd_rn(__fmul_rn(dx, dx), __fmul_rn(dy, dy)),
                     __fmul_rn(dz, dz));
}

// Cell coordinate via double so a float-rounding boundary crossing can't
// violate the "d2<25 => cell coords differ by <=1" coverage invariant.
__device__ __forceinline__ int cellOf(float v) {
    int c = (int)((double)v * 0.2);  // v in [0,45) -> c in [0,8]
    return c < 0 ? 0 : (c > NC1 - 1 ? NC1 - 1 : c);
}

// ---------------------------------------------------------------------------
__global__ __launch_bounds__(256) void nl_init(float4* __restrict__ out) {
    // out layout (floats): [0,2*MAXP) edge_index -> -1, [2*MAXP,6*MAXP) -> 0
    const int total4 = 6 * MAXP / 4;  // 786432
    const int neg4   = 2 * MAXP / 4;  // 262144
    const float4 negv  = make_float4(-1.f, -1.f, -1.f, -1.f);
    const float4 zerov = make_float4(0.f, 0.f, 0.f, 0.f);
    int idx = blockIdx.x * blockDim.x + threadIdx.x;
    int stride = gridDim.x * blockDim.x;
    for (int k = idx; k < total4; k += stride)
        out[k] = (k < neg4) ? negv : zerov;
}

// ---------------------------------------------------------------------------
// One block: histogram -> scan -> scatter atoms into cell-sorted arrays.
__global__ __launch_bounds__(1024) void bin_all(const float* __restrict__ pos,
                                                int* __restrict__ cellStart,
                                                int* __restrict__ sortedIdx,
                                                float4* __restrict__ sortedPos) {
    __shared__ unsigned int hist[NCELL];
    __shared__ unsigned int scanbuf[1024];
    __shared__ unsigned int starts[NCELL + 1];
    const int t = threadIdx.x;
    if (t < NCELL) hist[t] = 0u;
    __syncthreads();
    int myCell[8], mySlot[8];
#pragma unroll
    for (int k = 0; k < 8; ++k) {
        const int a = t + k * 1024;
        const float x = pos[3 * a], y = pos[3 * a + 1], z = pos[3 * a + 2];
        const int c = (cellOf(z) * NC1 + cellOf(y)) * NC1 + cellOf(x);
        myCell[k] = c;
        mySlot[k] = (int)atomicAdd(&hist[c], 1u);
    }
    __syncthreads();
    const unsigned int v = (t < NCELL) ? hist[t] : 0u;
    scanbuf[t] = v;
    __syncthreads();
    for (int off = 1; off < 1024; off <<= 1) {
        const unsigned int u = (t >= off) ? scanbuf[t - off] : 0u;
        __syncthreads();
        scanbuf[t] += u;
        __syncthreads();
    }
    const unsigned int ex = scanbuf[t] - v;  // exclusive prefix
    if (t < NCELL) { starts[t] = ex; cellStart[t] = (int)ex; }
    if (t == 0)    { starts[NCELL] = NATOMS; cellStart[NCELL] = NATOMS; }
    __syncthreads();
#pragma unroll
    for (int k = 0; k < 8; ++k) {
        const int a = t + k * 1024;
        const int p = (int)starts[myCell[k]] + mySlot[k];
        sortedIdx[p] = a;
        sortedPos[p] = make_float4(pos[3 * a], pos[3 * a + 1], pos[3 * a + 2], 0.f);
    }
}

// ---------------------------------------------------------------------------
// One wave per row i: test ~27-cell candidates, set bits in an 8192-bit LDS
// bitmap, then emit j's in ascending order (deterministic, matches nonzero()).
__global__ __launch_bounds__(512) void nl_neigh(const float* __restrict__ pos,
                                                const int* __restrict__ batch,
                                                const int* __restrict__ cellStart,
                                                const int* __restrict__ sortedIdx,
                                                const float4* __restrict__ sortedPos,
                                                unsigned short* __restrict__ rowbuf,
                                                int* __restrict__ counts) {
    __shared__ unsigned int bm[8][256];
    const int tid = threadIdx.x;
    const int lane = tid & 63;
    const int wave = tid >> 6;
    const int i = blockIdx.x * 8 + wave;
    unsigned int* sb = bm[wave];
    sb[lane] = 0u; sb[lane + 64] = 0u; sb[lane + 128] = 0u; sb[lane + 192] = 0u;

    const float xi = pos[3 * i], yi = pos[3 * i + 1], zi = pos[3 * i + 2];
    const int bi = batch[i];
    const int cx = cellOf(xi), cy = cellOf(yi), cz = cellOf(zi);
    const int xlo = cx > 0 ? cx - 1 : 0;
    const int xhi = cx < NC1 - 1 ? cx + 1 : NC1 - 1;

    for (int dz = -1; dz <= 1; ++dz) {
        const int czz = cz + dz;
        if ((unsigned)czz > (unsigned)(NC1 - 1)) continue;
        for (int dy = -1; dy <= 1; ++dy) {
            const int cyy = cy + dy;
            if ((unsigned)cyy > (unsigned)(NC1 - 1)) continue;
            const int base = (czz * NC1 + cyy) * NC1;
            const int s = cellStart[base + xlo];
            const int e = cellStart[base + xhi + 1];
            for (int k = s + lane; k < e; k += 64) {
                const float4 p = sortedPos[k];
                const int j = sortedIdx[k];
                const float dxv = xi - p.x;
                const float dyv = yi - p.y;
                const float dzv = zi - p.z;
                const float d2 = d2_exact(dxv, dyv, dzv);
                if (d2 < R2CUT && j != i && batch[j] == bi)
                    atomicOr(&sb[j >> 5], 1u << (j & 31));
            }
        }
    }

    // Emit ascending-j list. 256 u32 words -> 4 groups of 64 (one word/lane).
    unsigned short* rb = rowbuf + (size_t)i * ROWW;
    int total = 0;
#pragma unroll
    for (int g = 0; g < 4; ++g) {
        unsigned int w = sb[g * 64 + lane];
        const int c = __popc(w);
        int incl = c;
        for (int off = 1; off < 64; off <<= 1) {
            const int u = __shfl_up(incl, off);
            if (lane >= off) incl += u;
        }
        int o = total + incl - c;  // exclusive within row
        const unsigned int jbase = (unsigned)(g * 64 + lane) * 32u;
        while (w) {
            const int b = __ffs(w) - 1;
            w &= w - 1u;
            if (o < ROWW) rb[o] = (unsigned short)(jbase + (unsigned)b);
            ++o;
        }
        total += __shfl(incl, 63);
    }
    if (lane == 0) counts[i] = total > ROWW ? ROWW : total;
}

// ---------------------------------------------------------------------------
__global__ __launch_bounds__(256) void nl_scan(const int* __restrict__ counts,
                                               int* __restrict__ offsets) {
    __shared__ int ssum[256];
    const int tid = threadIdx.x;
    const int base = tid * 32;
    int c[32];
    int s = 0;
#pragma unroll
    for (int k = 0; k < 32; ++k) { c[k] = counts[base + k]; s += c[k]; }
    ssum[tid] = s;
    __syncthreads();
    for (int off = 1; off < 256; off <<= 1) {
        const int v = (tid >= off) ? ssum[tid - off] : 0;
        __syncthreads();
        ssum[tid] += v;
        __syncthreads();
    }
    int run = ssum[tid] - s;  // exclusive
#pragma unroll
    for (int k = 0; k < 32; ++k) { offsets[base + k] = run; run += c[k]; }
}

// ---------------------------------------------------------------------------
// One wave per row: recompute edge data from (i,j) with exact rounding, write
// to compacted output slots.
__global__ __launch_bounds__(512) void nl_scatter(const float* __restrict__ pos,
                                                  const unsigned short* __restrict__ rowbuf,
                                                  const int* __restrict__ counts,
                                                  const int* __restrict__ offsets,
                                                  float* __restrict__ out) {
    const int tid = threadIdx.x;
    const int lane = tid & 63;
    const int wave = tid >> 6;
    const int i = blockIdx.x * 8 + wave;
    const int cnt = counts[i];
    const int base = offsets[i];
    const float xi = pos[3 * i], yi = pos[3 * i + 1], zi = pos[3 * i + 2];
    const float fi = (float)i;
    const unsigned short* rb = rowbuf + (size_t)i * ROWW;
    float* __restrict__ outI = out;
    float* __restrict__ outJ = out + MAXP;
    float* __restrict__ outW = out + 2 * MAXP;
    float* __restrict__ outV = out + 3 * MAXP;
    for (int k = lane; k < cnt; k += 64) {
        const int j = rb[k];
        const float dxv = xi - pos[3 * j];
        const float dyv = yi - pos[3 * j + 1];
        const float dzv = zi - pos[3 * j + 2];
        const float d2 = d2_exact(dxv, dyv, dzv);
        const int slot = base + k;
        if (slot < MAXP) {
            outI[slot] = fi;
            outJ[slot] = (float)j;
            outW[slot] = sqrtf(d2);
            outV[3 * slot + 0] = dxv;
            outV[3 * slot + 1] = dyv;
            outV[3 * slot + 2] = dzv;
        }
    }
}

// ---------------------------------------------------------------------------
extern "C" void kernel_launch(void* const* d_in, const int* in_sizes, int n_in,
                              void* d_out, int out_size, void* d_ws, size_t ws_size,
                              hipStream_t stream) {
    const float* pos = (const float*)d_in[0];
    const int* batch = (const int*)d_in[1];
    float* out = (float*)d_out;

    // Workspace layout (bytes from d_ws):
    char* ws = (char*)d_ws;
    int* counts           = (int*)(ws);                    // 32 KB
    int* offsets          = (int*)(ws + (32 << 10));       // 32 KB
    int* cellStart        = (int*)(ws + (64 << 10));       // 4 KB (730 ints)
    int* sortedIdx        = (int*)(ws + (68 << 10));       // 32 KB
    float4* sortedPos     = (float4*)(ws + (100 << 10));   // 128 KB (16B aligned)
    unsigned short* rowbuf = (unsigned short*)(ws + (240 << 10));  // 2 MB

    nl_init<<<2048, 256, 0, stream>>>((float4*)out);
    bin_all<<<1, 1024, 0, stream>>>(pos, cellStart, sortedIdx, sortedPos);
    nl_neigh<<<NATOMS / 8, 512, 0, stream>>>(pos, batch, cellStart, sortedIdx,
                                             sortedPos, rowbuf, counts);
    nl_scan<<<1, 256, 0, stream>>>(counts, offsets);
    nl_scatter<<<NATOMS / 8, 512, 0, stream>>>(pos, rowbuf, counts, offsets, out);
}